// Round 8
// baseline (310.327 us; speedup 1.0000x reference)
//
#include <hip/hip_runtime.h>

// PSAMask collect: out[n, i*65+j, h, w] = x[n, (i-h+64)*129 + (j-w+64), h, w]
// R8: STREAMING-WRITE restructure. Block = (n, i, h-group of 7). For each
// output channel q=(i,j), positions (h,w) for h in the group are CONTIGUOUS
// (p = h*65+w) -> per j one 1820B contiguous write run; hg-adjacent blocks
// extend the same runs. Reads unchanged (131B trapezoid segments, 7 planes).
// LDS = 7 packed trapezoids (prefix layout) = 118.3KB, 1 block/CU, 16 waves.

constexpr int H = 65, W = 65, MH = 129, MW = 129, HALF = 64;
constexpr int HW = H * W;          // 4225
constexpr int PLANE = HW;          // packed trapezoid floats per h-plane
constexpr int TH = 7;              // h per block (last group: 2)
constexpr int NHG = 10;            // 9 groups of 7 (h 0..62) + 1 group of 2 (h 63,64)
constexpr int NWG = 4 * H * NHG;   // 2600, %8 == 0

__device__ __forceinline__ void ldsld(const float* g, float* l) {
    __builtin_amdgcn_global_load_lds(
        (const __attribute__((address_space(1))) unsigned int*)g,
        (__attribute__((address_space(3))) unsigned int*)l, 4, 0, 0);
}

// prefix(u) = sum of row lengths L(v)=65-|v-64| for v<u  (packed row base)
__device__ __forceinline__ int prefix_of(int u) {
    return (u <= 64) ? (u * (u + 1)) >> 1
                     : HW - (((MH - u) * (MH + 1 - u)) >> 1);
}

__global__ __launch_bounds__(1024)
void psamask_collect(const float* __restrict__ x, float* __restrict__ out) {
    extern __shared__ float lds[];   // TH * 4225 * 4 = 118,300 B

    // XCD swizzle (2600 % 8 == 0 -> simple bijective chunking)
    int b = blockIdx.x;
    int l = (b & 7) * (NWG / 8) + (b >> 3);

    int n   = l / (H * NHG);
    int rem = l - n * (H * NHG);
    int i   = rem / NHG;
    int hg  = rem - i * NHG;           // innermost: hg-adjacent blocks extend runs
    int h0  = hg < 9 ? 7 * hg : 63;
    int cnt = hg < 9 ? 7 : 2;

    int wv   = threadIdx.x >> 6;       // 0..15
    int lane = threadIdx.x & 63;

    // ---- Stage: plane d (h = h0+d), rows u: packed dest lds[d*PLANE + prefix(u)].
    // Row (d,u): global cols [w0, w0+L) of channel (i-h+64, u), image row h.
    for (int idx = wv; idx < cnt * MH; idx += 16) {     // wave-uniform row desc
        int d = idx / MH;
        int u = idx - d * MH;
        int h = h0 + d;
        int w0 = HALF - u; if (w0 < 0) w0 = 0;
        int L  = W - (u < HALF ? HALF - u : u - HALF);  // 65 - |u-64|
        int pre = prefix_of(u);
        const float* rowp = x + ((size_t)(n * (MH * MW) + (i - h + HALF) * MW + u)) * HW
                              + h * W + w0;
        float* ldst = &lds[d * PLANE + pre];
        if (lane < L) ldsld(rowp + lane, ldst);
        if (L == 65 && lane == 0) ldsld(rowp + 64, ldst + 64);   // u==64 extra elem
    }
    __syncthreads();   // drains vmcnt(0): all planes resident

    // ---- Store: per channel q=(i,j), contiguous run r = d*65+w of cnt*65 floats.
    // src elem: u = j-w+64, packed col t = w - w0(u) = min(j,w).
    int RUN   = cnt * W;               // 455 or 130
    int total = W * RUN;               // 29575 or 8450
    float* dstb = out + (size_t)n * HW * HW + (size_t)(i * W) * HW + h0 * W;
    for (int f = (int)threadIdx.x; f < total; f += 1024) {
        int j = f / RUN;
        int r = f - j * RUN;
        int d = r / W;
        int w = r - d * W;
        int u = j - w + HALF;
        int t = j < w ? j : w;
        dstb[(size_t)j * HW + r] = lds[d * PLANE + prefix_of(u) + t];
    }
}

extern "C" void kernel_launch(void* const* d_in, const int* in_sizes, int n_in,
                              void* d_out, int out_size, void* d_ws, size_t ws_size,
                              hipStream_t stream) {
    const float* x = (const float*)d_in[0];
    float* out = (float*)d_out;
    (void)in_sizes; (void)n_in; (void)out_size; (void)d_ws; (void)ws_size;
    psamask_collect<<<dim3(NWG), dim3(1024), TH * PLANE * sizeof(float), stream>>>(x, out);
}

// Round 9
// 164.276 us; speedup vs baseline: 1.8891x; 1.8891x over previous
//
#include <hip/hip_runtime.h>

// PSAMask collect: out[n, i*65+j, h, w] = x[n, (i-h+64)*129 + (j-w+64), h, w]
// Mask window fully covers offsets -> pure gather, no masking.
// FINAL (R2 revert): block per (n,i,h); async global->LDS trapezoid staging
// (global_load_lds, no VGPR round-trip, all loads in flight until the
// barrier), skewed conflict-free LDS reads, coalesced row stores.
// Envelope proven load-bearing by R5-R8 ablations: 34KB LDS -> 4 blocks/CU
// (32 waves/CU, cross-block read/write overlap), h-innermost ordering
// (adjacent blocks' 260B write segments share L2 lines on one XCD).

constexpr int H = 65, W = 65, MH = 129, MW = 129, HALF = 64;
constexpr int HW = H * W;          // 4225
constexpr int PITCH = 66;          // skew-read lane delta -65 -> conflict-free

__global__ __launch_bounds__(512, 4)
void psamask_collect(const float* __restrict__ x, float* __restrict__ out) {
    __shared__ float lds[MH * PITCH];  // 34,056 B -> 4 blocks/CU

    // Bijective XCD-aware swizzle (nwg=16900, 16900%8==4 -> m204 formula)
    constexpr int NWG = 4 * H * H;
    constexpr int NX  = 8;
    constexpr int q   = NWG / NX;
    constexpr int r   = NWG % NX;
    int b   = blockIdx.x;
    int xcd = b % NX;
    int idx = b / NX;
    int logical = (xcd < r ? xcd * (q + 1) : r * (q + 1) + (xcd - r) * q) + idx;

    int n   = logical / (H * H);
    int rem = logical - n * (H * H);
    int i   = rem / H;
    int h   = rem - i * H;
    int Mh  = i - h + HALF;            // always in [0, 128]

    const float* src = x + (size_t)(n * (MH * MW) + Mh * MW) * HW + h * W;

    int wave = threadIdx.x >> 6;
    int lane = threadIdx.x & 63;
    // Async staging: row u used for w in [max(0,64-u), min(65,129-u)).
    // All loads issue with no intermediate waitcnt; __syncthreads drains vmcnt.
    for (int u = wave; u < MH; u += 8) {
        int lo = HALF - u; if (lo < 0) lo = 0;
        int hi = MH - u;   if (hi > W) hi = W;
        const float* rowp = src + (size_t)u * HW;
        for (int w0 = lo; w0 < hi; w0 += 64) {
            int w = w0 + lane;
            if (w < hi) {
                __builtin_amdgcn_global_load_lds(
                    (const __attribute__((address_space(1))) unsigned int*)(rowp + w),
                    (__attribute__((address_space(3))) unsigned int*)(&lds[u * PITCH + w0]),
                    4, 0, 0);
            }
        }
    }
    __syncthreads();

    // Store: out row (i*W+j, h, :) <- skewed LDS read, coalesced 65-float rows
    float* dst = out + (size_t)n * HW * HW + (size_t)(i * W) * HW + h * W;
    for (int f = threadIdx.x; f < W * W; f += 512) {
        int j = f / W;
        int w = f - j * W;
        dst[(size_t)j * HW + w] = lds[(j - w + HALF) * PITCH + w];
    }
}

extern "C" void kernel_launch(void* const* d_in, const int* in_sizes, int n_in,
                              void* d_out, int out_size, void* d_ws, size_t ws_size,
                              hipStream_t stream) {
    const float* x = (const float*)d_in[0];
    float* out = (float*)d_out;
    (void)in_sizes; (void)n_in; (void)out_size; (void)d_ws; (void)ws_size;
    psamask_collect<<<dim3(4 * H * H), dim3(512), 0, stream>>>(x, out);
}